// Round 1
// baseline (96.829 us; speedup 1.0000x reference)
//
#include <hip/hip_runtime.h>

// LIF constants (fp32): DT=1e-3, TAU_MEM_INV=200 -> 0.2 ; TAU_SYN_INV=400 -> decay 0.6
#define VM_K 0.2f
#define SYN_DECAY 0.6f
#define V_TH 1.0f

__global__ __launch_bounds__(256) void lif_scan_kernel(
    const float4* __restrict__ x, float4* __restrict__ out, int N4, int T)
{
    int idx = blockIdx.x * blockDim.x + threadIdx.x;
    if (idx >= N4) return;

    float4 v1 = make_float4(0.f, 0.f, 0.f, 0.f);
    float4 i1 = v1, v2 = v1, i2 = v1;

    const float4* xp = x + idx;
    float4* op = out + idx;

#pragma unroll 4
    for (int t = 0; t < T; ++t) {
        float4 xt = xp[(size_t)t * N4];
        float4 z2;

        // process 4 independent lanes (components of float4)
        {
            // component x
            float v1d = v1.x + VM_K * (i1.x - v1.x);
            float z1  = (v1d - V_TH > 0.f) ? 1.f : 0.f;
            v1.x = (1.f - z1) * v1d;
            i1.x = SYN_DECAY * i1.x + xt.x;
            float v2d = v2.x + VM_K * (i2.x - v2.x);
            float z2c = (v2d - V_TH > 0.f) ? 1.f : 0.f;
            v2.x = (1.f - z2c) * v2d;
            i2.x = SYN_DECAY * i2.x + z1;
            z2.x = z2c;
        }
        {
            float v1d = v1.y + VM_K * (i1.y - v1.y);
            float z1  = (v1d - V_TH > 0.f) ? 1.f : 0.f;
            v1.y = (1.f - z1) * v1d;
            i1.y = SYN_DECAY * i1.y + xt.y;
            float v2d = v2.y + VM_K * (i2.y - v2.y);
            float z2c = (v2d - V_TH > 0.f) ? 1.f : 0.f;
            v2.y = (1.f - z2c) * v2d;
            i2.y = SYN_DECAY * i2.y + z1;
            z2.y = z2c;
        }
        {
            float v1d = v1.z + VM_K * (i1.z - v1.z);
            float z1  = (v1d - V_TH > 0.f) ? 1.f : 0.f;
            v1.z = (1.f - z1) * v1d;
            i1.z = SYN_DECAY * i1.z + xt.z;
            float v2d = v2.z + VM_K * (i2.z - v2.z);
            float z2c = (v2d - V_TH > 0.f) ? 1.f : 0.f;
            v2.z = (1.f - z2c) * v2d;
            i2.z = SYN_DECAY * i2.z + z1;
            z2.z = z2c;
        }
        {
            float v1d = v1.w + VM_K * (i1.w - v1.w);
            float z1  = (v1d - V_TH > 0.f) ? 1.f : 0.f;
            v1.w = (1.f - z1) * v1d;
            i1.w = SYN_DECAY * i1.w + xt.w;
            float v2d = v2.w + VM_K * (i2.w - v2.w);
            float z2c = (v2d - V_TH > 0.f) ? 1.f : 0.f;
            v2.w = (1.f - z2c) * v2d;
            i2.w = SYN_DECAY * i2.w + z1;
            z2.w = z2c;
        }

        op[(size_t)t * N4] = z2;
    }
}

extern "C" void kernel_launch(void* const* d_in, const int* in_sizes, int n_in,
                              void* d_out, int out_size, void* d_ws, size_t ws_size,
                              hipStream_t stream) {
    const float* x = (const float*)d_in[0];
    float* out = (float*)d_out;

    // x: [T=256, B=16, H=128, W=128] fp32. Spatial elements per timestep:
    const int T = 256;
    const int N = in_sizes[0] / T;   // 262144
    const int N4 = N / 4;            // 65536 (N divisible by 4)

    const int block = 256;
    const int grid = (N4 + block - 1) / block;  // 256 blocks

    lif_scan_kernel<<<grid, block, 0, stream>>>(
        (const float4*)x, (float4*)out, N4, T);
}